// Round 2
// baseline (1521.996 us; speedup 1.0000x reference)
//
#include <hip/hip_runtime.h>
#include <hip/hip_bf16.h>

#define N_ 16
#define C_ 256
#define T_ 256
#define V_ 25
#define VP_ 20
#define S_ 3
#define IC_ 64

// ---------------- K1: xp = x @ w_e + b_e  (node remap V=25 -> VP=20) ----------------
__global__ __launch_bounds__(256) void k_conv_e(const float* __restrict__ x,
    const float* __restrict__ w_e, const float* __restrict__ b_e,
    float* __restrict__ xp)
{
    __shared__ __align__(16) float sw[V_*VP_];
    __shared__ float sb[VP_];
    int tid = threadIdx.x;
    for (int idx = tid; idx < V_*VP_; idx += 256) sw[idx] = w_e[idx];   // FIX: 500 > 256
    if (tid < VP_) sb[tid] = b_e[tid];
    __syncthreads();
    long row = (long)blockIdx.x * 256 + tid;   // (n,c,t) row, 1,048,576 total
    const float* xr = x + row * V_;
    float acc[VP_];
    #pragma unroll
    for (int u = 0; u < VP_; u++) acc[u] = sb[u];
    #pragma unroll
    for (int v = 0; v < V_; v++) {
        float xv = xr[v];
        const float4* w4 = (const float4*)&sw[v*VP_];
        #pragma unroll
        for (int q = 0; q < 5; q++) {
            float4 w = w4[q];
            acc[4*q+0] = fmaf(xv, w.x, acc[4*q+0]);
            acc[4*q+1] = fmaf(xv, w.y, acc[4*q+1]);
            acc[4*q+2] = fmaf(xv, w.z, acc[4*q+2]);
            acc[4*q+3] = fmaf(xv, w.w, acc[4*q+3]);
        }
    }
    float* outr = xp + row * VP_;
    #pragma unroll
    for (int u = 0; u < VP_; u++) outr[u] = acc[u];
}

// ---------------- K3: fa/fb (channel GEMMs) + scores contraction, fused per (n,t) ----
__global__ __launch_bounds__(192) void k_scores(const float* __restrict__ xp,
    const float* __restrict__ wa, const float* __restrict__ ba,
    const float* __restrict__ wb, const float* __restrict__ bb,
    float* __restrict__ scores)
{
    // smem union: phase 1 uses xt[256][24] (6144 floats); phase 2 uses fa/fb (7680 floats)
    __shared__ __align__(16) float smem[2*192*VP_];
    float* xt = smem;
    int nt = blockIdx.x;
    int n = nt >> 8, t = nt & 255;
    int tid = threadIdx.x;
    const float* xpb = xp + ((long)n*C_*T_ + t) * VP_;
    for (int idx = tid; idx < C_*VP_; idx += 192) {
        int c = idx / VP_, u = idx - c*VP_;
        xt[c*24 + u] = xpb[(long)c*T_*VP_ + u];
    }
    __syncthreads();
    int s = tid / IC_, i = tid - (tid / IC_)*IC_;
    float fa[VP_], fb[VP_];
    #pragma unroll
    for (int u = 0; u < VP_; u++) { fa[u] = 0.f; fb[u] = 0.f; }
    const float* war = wa + (s*IC_ + i)*C_;
    const float* wbr = wb + (s*IC_ + i)*C_;
    for (int c = 0; c < C_; c++) {
        float ra = war[c], rb = wbr[c];
        const float4* xr = (const float4*)&xt[c*24];
        #pragma unroll
        for (int q = 0; q < 5; q++) {
            float4 xv = xr[q];
            fa[4*q+0] = fmaf(ra, xv.x, fa[4*q+0]);
            fa[4*q+1] = fmaf(ra, xv.y, fa[4*q+1]);
            fa[4*q+2] = fmaf(ra, xv.z, fa[4*q+2]);
            fa[4*q+3] = fmaf(ra, xv.w, fa[4*q+3]);
            fb[4*q+0] = fmaf(rb, xv.x, fb[4*q+0]);
            fb[4*q+1] = fmaf(rb, xv.y, fb[4*q+1]);
            fb[4*q+2] = fmaf(rb, xv.z, fb[4*q+2]);
            fb[4*q+3] = fmaf(rb, xv.w, fb[4*q+3]);
        }
    }
    float bav = ba[s*IC_ + i], bbv = bb[s*IC_ + i];
    __syncthreads();   // everyone done reading xt; reuse smem for fa/fb
    #pragma unroll
    for (int u = 0; u < VP_; u++) {
        smem[tid*VP_ + u]         = fa[u] + bav;   // fa[s][i][u] at (s*64+i)=tid
        smem[(192 + tid)*VP_ + u] = fb[u] + bbv;
    }
    __syncthreads();
    float* scb = scores + n * (S_*VP_*VP_);
    for (int item = tid; item < S_*VP_*VP_; item += 192) {
        int ss = item / (VP_*VP_);
        int r  = item - ss*(VP_*VP_);
        int v  = r / VP_, u = r - (r / VP_)*VP_;
        const float* fap = &smem[(ss*IC_)*VP_ + v];
        const float* fbp = &smem[(192 + ss*IC_)*VP_ + u];
        float acc = 0.f;
        #pragma unroll 8
        for (int ii = 0; ii < IC_; ii++)
            acc = fmaf(fap[ii*VP_], fbp[ii*VP_], acc);
        atomicAdd(&scb[item], acc);
    }
}

// ---------------- K4: att = softmax_v(scores/(IC*T)) + (A_fix + PA) ------------------
__global__ void k_att(const float* __restrict__ scores, const float* __restrict__ PA,
    const float* __restrict__ A_fix, float* __restrict__ att)
{
    int ns = blockIdx.x;              // n*S_+s
    int s = ns - (ns / S_)*S_;
    int u = threadIdx.x;
    if (u >= VP_) return;
    const float* sc = scores + ns*VP_*VP_;
    const float inv = 1.0f / (IC_*T_);
    float m = -1e30f;
    for (int v = 0; v < VP_; v++) m = fmaxf(m, sc[v*VP_+u]);
    m *= inv;
    float e[VP_]; float sum = 0.f;
    for (int v = 0; v < VP_; v++) { float t = __expf(sc[v*VP_+u]*inv - m); e[v] = t; sum += t; }
    float r = 1.0f / sum;
    const float* Ab = A_fix + s*VP_*VP_;
    const float* Pb = PA    + s*VP_*VP_;
    float* ob = att + ns*VP_*VP_;
    for (int v = 0; v < VP_; v++) ob[v*VP_+u] = e[v]*r + Ab[v*VP_+u] + Pb[v*VP_+u];
}

// ---------------- K5: y = sum_s wd[s] @ (xt @ att[n,s]) + bd_sum, per (n,t) ----------
__global__ __launch_bounds__(128) void k_y(const float* __restrict__ xp,
    const float* __restrict__ att, const float* __restrict__ wd,
    const float* __restrict__ bd, float* __restrict__ y)
{
    __shared__ __align__(16) float xt[C_*21];        // pad 21: conflict-free per-lane rows
    __shared__ __align__(16) float zt[C_*VP_];       // rows 80B, 16B-aligned for float4 bcast
    __shared__ __align__(16) float attl[S_*VP_*VP_];
    int nt = blockIdx.x;
    int n = nt >> 8, t = nt & 255;
    int tid = threadIdx.x;
    const float* xpb = xp + ((long)n*C_*T_ + t) * VP_;
    for (int idx = tid; idx < C_*VP_; idx += 128) {
        int c = idx / VP_, u = idx - (idx / VP_)*VP_;
        xt[c*21 + u] = xpb[(long)c*T_*VP_ + u];
    }
    for (int idx = tid; idx < S_*VP_*VP_; idx += 128)
        attl[idx] = att[(long)n*S_*VP_*VP_ + idx];
    __syncthreads();
    int o0 = tid, o1 = tid + 128;
    float b0 = bd[o0] + bd[C_+o0] + bd[2*C_+o0];
    float b1 = bd[o1] + bd[C_+o1] + bd[2*C_+o1];
    float acc0[VP_], acc1[VP_];
    #pragma unroll
    for (int u = 0; u < VP_; u++) { acc0[u] = b0; acc1[u] = b1; }
    for (int s = 0; s < S_; s++) {
        if (s) __syncthreads();            // zt reads of previous s complete
        #pragma unroll
        for (int half = 0; half < 2; half++) {
            int c = tid + half*128;
            float z[VP_];
            #pragma unroll
            for (int u = 0; u < VP_; u++) z[u] = 0.f;
            const float* arow = &attl[s*VP_*VP_];
            #pragma unroll 4
            for (int v = 0; v < VP_; v++) {
                float xv = xt[c*21 + v];
                const float4* a4 = (const float4*)&arow[v*VP_];
                #pragma unroll
                for (int q = 0; q < 5; q++) {
                    float4 av = a4[q];
                    z[4*q+0] = fmaf(xv, av.x, z[4*q+0]);
                    z[4*q+1] = fmaf(xv, av.y, z[4*q+1]);
                    z[4*q+2] = fmaf(xv, av.z, z[4*q+2]);
                    z[4*q+3] = fmaf(xv, av.w, z[4*q+3]);
                }
            }
            #pragma unroll
            for (int u = 0; u < VP_; u++) zt[c*VP_ + u] = z[u];
        }
        __syncthreads();
        const float* wr0 = wd + (long)(s*C_ + o0)*C_;
        const float* wr1 = wd + (long)(s*C_ + o1)*C_;
        #pragma unroll 8
        for (int c = 0; c < C_; c++) {
            float w0 = wr0[c], w1 = wr1[c];
            const float4* z4 = (const float4*)&zt[c*VP_];
            #pragma unroll
            for (int q = 0; q < 5; q++) {
                float4 zv = z4[q];
                acc0[4*q+0] = fmaf(w0, zv.x, acc0[4*q+0]);
                acc0[4*q+1] = fmaf(w0, zv.y, acc0[4*q+1]);
                acc0[4*q+2] = fmaf(w0, zv.z, acc0[4*q+2]);
                acc0[4*q+3] = fmaf(w0, zv.w, acc0[4*q+3]);
                acc1[4*q+0] = fmaf(w1, zv.x, acc1[4*q+0]);
                acc1[4*q+1] = fmaf(w1, zv.y, acc1[4*q+1]);
                acc1[4*q+2] = fmaf(w1, zv.z, acc1[4*q+2]);
                acc1[4*q+3] = fmaf(w1, zv.w, acc1[4*q+3]);
            }
        }
    }
    float* yb = y + ((long)n*C_*T_ + t) * VP_;
    #pragma unroll
    for (int u = 0; u < VP_; u++) {
        yb[(long)o0*T_*VP_ + u] = acc0[u];
        yb[(long)o1*T_*VP_ + u] = acc1[u];
    }
}

// ---------------- K6: BN batch stats per channel -> fused scale/shift ----------------
__global__ __launch_bounds__(256) void k_bnstat(const float* __restrict__ y,
    const float* __restrict__ gamma, const float* __restrict__ beta,
    float* __restrict__ scale, float* __restrict__ shift)
{
    int o = blockIdx.x, tid = threadIdx.x;
    float sum = 0.f, sq = 0.f;
    for (int n = 0; n < N_; n++) {
        const float4* p = (const float4*)(y + (long)(n*C_ + o)*T_*VP_);
        for (int idx = tid; idx < T_*VP_/4; idx += 256) {
            float4 v = p[idx];
            sum += v.x + v.y + v.z + v.w;
            sq  += v.x*v.x + v.y*v.y + v.z*v.z + v.w*v.w;
        }
    }
    __shared__ float s1[256], s2[256];
    s1[tid] = sum; s2[tid] = sq;
    __syncthreads();
    for (int off = 128; off > 0; off >>= 1) {
        if (tid < off) { s1[tid] += s1[tid+off]; s2[tid] += s2[tid+off]; }
        __syncthreads();
    }
    if (tid == 0) {
        const float M = (float)(N_*T_*VP_);
        float mean = s1[0] / M;
        float var  = s2[0] / M - mean*mean;
        float g = gamma[o] * rsqrtf(var + 1e-5f);
        scale[o] = g;
        shift[o] = beta[o] - mean*g;
    }
}

// ---------------- K7: out = relu(y*scale + shift + xp), in-place on d_out ------------
__global__ void k_final(float* __restrict__ out, const float* __restrict__ xp,
    const float* __restrict__ scale, const float* __restrict__ shift)
{
    const long total4 = (long)N_*C_*T_*VP_/4;
    long stride = (long)gridDim.x * blockDim.x;
    for (long i4 = (long)blockIdx.x*blockDim.x + threadIdx.x; i4 < total4; i4 += stride) {
        int c = (int)((i4 / (T_*VP_/4)) & (C_-1));
        float4 v  = ((const float4*)out)[i4];
        float4 xv = ((const float4*)xp)[i4];
        float sc = scale[c], sh = shift[c];
        v.x = fmaxf(fmaf(v.x, sc, sh) + xv.x, 0.f);
        v.y = fmaxf(fmaf(v.y, sc, sh) + xv.y, 0.f);
        v.z = fmaxf(fmaf(v.z, sc, sh) + xv.z, 0.f);
        v.w = fmaxf(fmaf(v.w, sc, sh) + xv.w, 0.f);
        ((float4*)out)[i4] = v;
    }
}

extern "C" void kernel_launch(void* const* d_in, const int* in_sizes, int n_in,
                              void* d_out, int out_size, void* d_ws, size_t ws_size,
                              hipStream_t stream)
{
    const float* x     = (const float*)d_in[0];
    const float* PA    = (const float*)d_in[1];
    const float* A_fix = (const float*)d_in[2];
    const float* w_e   = (const float*)d_in[3];
    const float* b_e   = (const float*)d_in[4];
    const float* wa    = (const float*)d_in[5];
    const float* ba    = (const float*)d_in[6];
    const float* wb    = (const float*)d_in[7];
    const float* bb    = (const float*)d_in[8];
    const float* wd    = (const float*)d_in[9];
    const float* bd    = (const float*)d_in[10];
    const float* gamma = (const float*)d_in[11];
    const float* beta  = (const float*)d_in[12];
    float* out = (float*)d_out;

    char* ws = (char*)d_ws;
    const size_t XP_BYTES = (size_t)N_*C_*T_*VP_*sizeof(float);   // 83,886,080
    const size_t SC_BYTES = (size_t)N_*S_*VP_*VP_*sizeof(float);  // 76,800
    float* xp     = (float*)(ws);
    float* scores = (float*)(ws + XP_BYTES);
    float* att    = (float*)(ws + XP_BYTES + SC_BYTES);
    float* scale  = (float*)(ws + XP_BYTES + 2*SC_BYTES);
    float* shift  = scale + C_;

    k_conv_e<<<4096, 256, 0, stream>>>(x, w_e, b_e, xp);
    hipMemsetAsync(scores, 0, SC_BYTES, stream);
    k_scores<<<N_*T_, 192, 0, stream>>>(xp, wa, ba, wb, bb, scores);
    k_att<<<N_*S_, 32, 0, stream>>>(scores, PA, A_fix, att);
    k_y<<<N_*T_, 128, 0, stream>>>(xp, att, wd, bd, out);
    k_bnstat<<<C_, 256, 0, stream>>>(out, gamma, beta, scale, shift);
    k_final<<<2048, 256, 0, stream>>>(out, xp, scale, shift);
}

// Round 3
// 828.425 us; speedup vs baseline: 1.8372x; 1.8372x over previous
//
#include <hip/hip_runtime.h>

typedef unsigned short u16;
typedef unsigned int u32;
typedef float __attribute__((ext_vector_type(4))) f32x4;
typedef short __attribute__((ext_vector_type(8))) s16x8;

#define N_ 16
#define C_ 256
#define T_ 256
#define V_ 25
#define VP_ 20
#define S_ 3
#define IC_ 64
#define M_ (T_*VP_)      // 5120 spatial per n
#define WROWS 1152       // 192 fa + 192 fb + 768 g rows

__device__ __forceinline__ u16 f2bf(float f) {
    u32 u = __float_as_uint(f);
    u32 r = (u + 0x7FFFu + ((u >> 16) & 1u)) >> 16;
    return (u16)r;
}
__device__ __forceinline__ float bf2f(u16 h) {
    return __uint_as_float(((u32)h) << 16);
}

// ---------- K1: xp_bf16[n][c][t][v] = x @ w_e + b_e ----------
__global__ __launch_bounds__(256) void k_conv_e(const float* __restrict__ x,
    const float* __restrict__ w_e, const float* __restrict__ b_e, u16* __restrict__ xp)
{
    __shared__ __align__(16) float sw[V_*VP_];
    __shared__ float sb[VP_];
    int tid = threadIdx.x;
    for (int i = tid; i < V_*VP_; i += 256) sw[i] = w_e[i];
    if (tid < VP_) sb[tid] = b_e[tid];
    __syncthreads();
    long row = (long)blockIdx.x*256 + tid;     // (n,c,t) row
    const float* xr = x + row*V_;
    float acc[VP_];
    #pragma unroll
    for (int u = 0; u < VP_; u++) acc[u] = sb[u];
    #pragma unroll
    for (int v = 0; v < V_; v++) {
        float xv = xr[v];
        const float4* w4 = (const float4*)&sw[v*VP_];
        #pragma unroll
        for (int q = 0; q < 5; q++) {
            float4 w = w4[q];
            acc[4*q+0] = fmaf(xv, w.x, acc[4*q+0]);
            acc[4*q+1] = fmaf(xv, w.y, acc[4*q+1]);
            acc[4*q+2] = fmaf(xv, w.z, acc[4*q+2]);
            acc[4*q+3] = fmaf(xv, w.w, acc[4*q+3]);
        }
    }
    u32 ub[10];
    #pragma unroll
    for (int q = 0; q < 10; q++)
        ub[q] = (u32)f2bf(acc[2*q]) | ((u32)f2bf(acc[2*q+1]) << 16);
    uint2* o2 = (uint2*)(xp + row*VP_);
    #pragma unroll
    for (int q = 0; q < 5; q++) o2[q] = make_uint2(ub[2*q], ub[2*q+1]);
}

// ---------- K2: pack weights [wa;wb;wd] -> bf16 [1152][256] + bias vector ----------
__global__ void k_packW(const float* __restrict__ wa, const float* __restrict__ wb,
    const float* __restrict__ wd, const float* __restrict__ ba, const float* __restrict__ bb,
    u16* __restrict__ Wb, float* __restrict__ biasv)
{
    int row = blockIdx.x, c = threadIdx.x;
    const float* src = (row < 192) ? (wa + (long)row*C_)
                     : (row < 384) ? (wb + (long)(row-192)*C_)
                                   : (wd + (long)(row-384)*C_);
    Wb[(long)row*C_ + c] = f2bf(src[c]);
    if (c == 0) biasv[row] = (row < 192) ? ba[row] : ((row < 384) ? bb[row-192] : 0.f);
}

// ---------- K3: xpT[n][m][c] = xp[n][c][m], 64x64 tiles ----------
__global__ __launch_bounds__(256) void k_tr(const u16* __restrict__ xp, u16* __restrict__ xpT)
{
    __shared__ __align__(16) u16 tile[64*68];
    int bid = blockIdx.x;
    int cb = bid & 3, mb = (bid >> 2) % 80, n = bid / 320;
    int c0 = cb*64, m0 = mb*64;
    int tid = threadIdx.x;
    int rr = tid >> 4;            // 0..15
    int q4 = (tid & 15) * 4;      // 0..60
    const u16* xin = xp + (long)n*C_*M_;
    #pragma unroll
    for (int p = 0; p < 4; p++) {
        int c = p*16 + rr;
        uint2 rv = *(const uint2*)(xin + (long)(c0+c)*M_ + m0 + q4);
        *(uint2*)(&tile[c*68 + q4]) = rv;
    }
    __syncthreads();
    u16* xout = xpT + (long)n*M_*C_;
    #pragma unroll
    for (int p = 0; p < 4; p++) {
        int m = p*16 + rr;
        u32 u0 = (u32)tile[(q4+0)*68 + m] | ((u32)tile[(q4+1)*68 + m] << 16);
        u32 u1 = (u32)tile[(q4+2)*68 + m] | ((u32)tile[(q4+3)*68 + m] << 16);
        *(uint2*)(xout + (long)(m0+m)*C_ + c0 + q4) = make_uint2(u0, u1);
    }
}

// ---------- K4: fafbg[n][1152][5120] = Wb @ xp  (MFMA, 128x128 tile, BK=64) ----------
__global__ __launch_bounds__(256) void k_gemm(const u16* __restrict__ Wb,
    const u16* __restrict__ xpT, const float* __restrict__ biasv, u16* __restrict__ out)
{
    __shared__ __align__(16) short smem[128*64 + 128*64];   // 32 KB
    short* As = smem;
    short* Bs = smem + 128*64;
    int bid = blockIdx.x;
    int nb = bid % 40;
    int mb = (bid / 40) % 9;
    int n  = bid / 360;
    int tid = threadIdx.x;
    int wid = tid >> 6, lane = tid & 63;
    int wr = wid >> 1, wc = wid & 1;

    float biasr[4][4];
    {
        int rbase = mb*128 + wr*64 + ((lane >> 4) << 2);
        #pragma unroll
        for (int m = 0; m < 4; m++)
            #pragma unroll
            for (int r = 0; r < 4; r++)
                biasr[m][r] = biasv[rbase + m*16 + r];
    }
    const u16* Ag = Wb + (long)mb*128*C_;
    const u16* Bg = xpT + ((long)n*M_ + (long)nb*128)*C_;

    f32x4 acc[4][4];
    #pragma unroll
    for (int m = 0; m < 4; m++)
        #pragma unroll
        for (int nf = 0; nf < 4; nf++)
            acc[m][nf] = f32x4{0.f, 0.f, 0.f, 0.f};

    auto stage = [&](int k0) {
        #pragma unroll
        for (int j = 0; j < 4; j++) {
            int L = j*256 + wid*64 + lane;
            int row = L >> 3, ko = (L & 7) * 8;
            __builtin_amdgcn_global_load_lds(
                (const unsigned int*)(Ag + (long)row*C_ + k0 + ko),
                (unsigned int*)(As + (j*256 + wid*64)*8), 16, 0, 0);
            __builtin_amdgcn_global_load_lds(
                (const unsigned int*)(Bg + (long)row*C_ + k0 + ko),
                (unsigned int*)(Bs + (j*256 + wid*64)*8), 16, 0, 0);
        }
    };

    stage(0);
    __syncthreads();
    for (int kt = 0; kt < 4; kt++) {
        #pragma unroll
        for (int ks = 0; ks < 2; ks++) {
            s16x8 af[4], bg[4];
            #pragma unroll
            for (int m = 0; m < 4; m++)
                af[m] = *(const s16x8*)(As + (wr*64 + m*16 + (lane & 15))*64 + ks*32 + ((lane >> 4) << 3));
            #pragma unroll
            for (int nf = 0; nf < 4; nf++)
                bg[nf] = *(const s16x8*)(Bs + (wc*64 + nf*16 + (lane & 15))*64 + ks*32 + ((lane >> 4) << 3));
            #pragma unroll
            for (int m = 0; m < 4; m++)
                #pragma unroll
                for (int nf = 0; nf < 4; nf++)
                    acc[m][nf] = __builtin_amdgcn_mfma_f32_16x16x32_bf16(af[m], bg[nf], acc[m][nf], 0, 0, 0);
        }
        if (kt < 3) {
            __syncthreads();
            stage((kt+1)*64);
            __syncthreads();
        }
    }
    __syncthreads();
    // epilogue: frags -> LDS bf16 C-tile -> coalesced global store
    u16* Cs = (u16*)smem;
    #pragma unroll
    for (int m = 0; m < 4; m++)
        #pragma unroll
        for (int nf = 0; nf < 4; nf++)
            #pragma unroll
            for (int r = 0; r < 4; r++) {
                int row = wr*64 + m*16 + ((lane >> 4) << 2) + r;
                int col = wc*64 + nf*16 + (lane & 15);
                Cs[row*128 + col] = f2bf(acc[m][nf][r] + biasr[m][r]);
            }
    __syncthreads();
    u16* og = out + ((long)n*WROWS + (long)mb*128)*M_ + (long)nb*128;
    #pragma unroll
    for (int j = 0; j < 8; j++) {
        int idx = j*256 + tid;
        int row = idx >> 4, c8 = (idx & 15) * 8;
        uint4 v = *(const uint4*)(Cs + row*128 + c8);
        *(uint4*)(og + (long)row*M_ + c8) = v;
    }
}

// ---------- K5: scores[n][s][v][u] += sum_{i,t} fa[i,t,v]*fb[i,t,u] ----------
__global__ __launch_bounds__(256) void k_scores_red(const u16* __restrict__ fafbg,
    float* __restrict__ scores)
{
    int bid = blockIdx.x;            // n*24 + s*8 + tc
    int tc = bid & 7;
    int s  = (bid >> 3) % 3;
    int n  = bid / 24;
    int tid = threadIdx.x;
    int w = tid >> 6, lane = tid & 63;
    int h = w & 1;                   // v-half
    int pair = w >> 1;               // k-half of this block's 2048 k's
    const uint2* fa2 = (const uint2*)(fafbg + ((long)n*WROWS + s*IC_)*M_);
    const uint2* fb2 = (const uint2*)(fafbg + ((long)n*WROWS + 192 + s*IC_)*M_);
    int t0 = tc*32;
    float acc[10][20];
    #pragma unroll
    for (int vi = 0; vi < 10; vi++)
        #pragma unroll
        for (int u = 0; u < 20; u++) acc[vi][u] = 0.f;

    for (int j = 0; j < 16; j++) {
        int kl = pair*1024 + j*64 + lane;
        int i = kl >> 5, tt = kl & 31;
        long off = (long)i*1280 + (long)(t0+tt)*5;      // uint2 units
        uint2 A[5], B[5];
        #pragma unroll
        for (int q = 0; q < 5; q++) { A[q] = fa2[off+q]; B[q] = fb2[off+q]; }
        float fav[20], fbv[20];
        #pragma unroll
        for (int q = 0; q < 5; q++) {
            fav[4*q+0] = bf2f((u16)A[q].x); fav[4*q+1] = bf2f((u16)(A[q].x >> 16));
            fav[4*q+2] = bf2f((u16)A[q].y); fav[4*q+3] = bf2f((u16)(A[q].y >> 16));
            fbv[4*q+0] = bf2f((u16)B[q].x); fbv[4*q+1] = bf2f((u16)(B[q].x >> 16));
            fbv[4*q+2] = bf2f((u16)B[q].y); fbv[4*q+3] = bf2f((u16)(B[q].y >> 16));
        }
        float fsel[10];
        #pragma unroll
        for (int vi = 0; vi < 10; vi++) fsel[vi] = h ? fav[10+vi] : fav[vi];
        #pragma unroll
        for (int vi = 0; vi < 10; vi++)
            #pragma unroll
            for (int u = 0; u < 20; u++)
                acc[vi][u] = fmaf(fsel[vi], fbv[u], acc[vi][u]);
    }
    // butterfly over low 3 lane bits -> 8-lane-group partials, then grouped atomics
    #pragma unroll
    for (int mm = 1; mm < 8; mm <<= 1)
        #pragma unroll
        for (int vi = 0; vi < 10; vi++)
            #pragma unroll
            for (int u = 0; u < 20; u++)
                acc[vi][u] += __shfl_xor(acc[vi][u], mm);
    float* scb = scores + ((long)(n*S_ + s)*VP_ + h*10)*VP_;
    if ((lane & 7) == 0) {
        #pragma unroll
        for (int vi = 0; vi < 10; vi++)
            #pragma unroll
            for (int u = 0; u < 20; u++)
                atomicAdd(&scb[vi*VP_ + u], acc[vi][u]);
    }
}

// ---------- K6: att = softmax_v(scores/(IC*T)) + (A_fix + PA) ----------
__global__ void k_att(const float* __restrict__ scores, const float* __restrict__ PA,
    const float* __restrict__ A_fix, float* __restrict__ att)
{
    int ns = blockIdx.x;
    int s = ns - (ns / S_)*S_;
    int u = threadIdx.x;
    if (u >= VP_) return;
    const float* sc = scores + (long)ns*VP_*VP_;
    const float inv = 1.0f / (IC_*T_);
    float m = -1e30f;
    for (int v = 0; v < VP_; v++) m = fmaxf(m, sc[v*VP_+u]);
    m *= inv;
    float e[VP_]; float sum = 0.f;
    for (int v = 0; v < VP_; v++) { float t = __expf(sc[v*VP_+u]*inv - m); e[v] = t; sum += t; }
    float r = 1.0f / sum;
    const float* Ab = A_fix + s*VP_*VP_;
    const float* Pb = PA    + s*VP_*VP_;
    float* ob = att + (long)ns*VP_*VP_;
    for (int v = 0; v < VP_; v++) ob[v*VP_+u] = e[v]*r + Ab[v*VP_+u] + Pb[v*VP_+u];
}

// ---------- K7: y[n][o][t][u] = sum_{s,v} g[s,o,t,v]*att[s,v,u] + bd_sum ----------
__global__ __launch_bounds__(128) void k_comb(const u16* __restrict__ fafbg,
    const float* __restrict__ att, const float* __restrict__ bd, float* __restrict__ out)
{
    __shared__ __align__(16) u16 gsh[S_*C_*VP_];       // 30720 B
    __shared__ __align__(16) float attsh[S_*VP_*VP_];  // 4800 B
    int nt = blockIdx.x, n = nt >> 8, t = nt & 255;
    int tid = threadIdx.x;
    for (int i = tid; i < S_*VP_*VP_; i += 128) attsh[i] = att[(long)n*S_*VP_*VP_ + i];
    const u32* gbase = (const u32*)fafbg;
    u32* gsh32 = (u32*)gsh;
    for (int j = 0; j < 60; j++) {
        int idx = j*128 + tid;
        int r = idx / 10, d = idx - r*10;
        gsh32[idx] = gbase[(long)(n*WROWS + 384 + r)*2560 + t*10 + d];
    }
    __syncthreads();
    int o0 = tid, o1 = tid + 128;
    float acc0[VP_], acc1[VP_];
    {
        float bs0 = bd[o0] + bd[C_+o0] + bd[2*C_+o0];
        float bs1 = bd[o1] + bd[C_+o1] + bd[2*C_+o1];
        #pragma unroll
        for (int u = 0; u < VP_; u++) { acc0[u] = bs0; acc1[u] = bs1; }
    }
    for (int s = 0; s < S_; s++) {
        #pragma unroll
        for (int v = 0; v < VP_; v++) {
            const float4* ar = (const float4*)&attsh[(s*VP_+v)*VP_];
            float g0 = bf2f(gsh[(s*C_+o0)*VP_ + v]);
            float g1 = bf2f(gsh[(s*C_+o1)*VP_ + v]);
            #pragma unroll
            for (int q = 0; q < 5; q++) {
                float4 a = ar[q];
                acc0[4*q+0] = fmaf(g0, a.x, acc0[4*q+0]);
                acc0[4*q+1] = fmaf(g0, a.y, acc0[4*q+1]);
                acc0[4*q+2] = fmaf(g0, a.z, acc0[4*q+2]);
                acc0[4*q+3] = fmaf(g0, a.w, acc0[4*q+3]);
                acc1[4*q+0] = fmaf(g1, a.x, acc1[4*q+0]);
                acc1[4*q+1] = fmaf(g1, a.y, acc1[4*q+1]);
                acc1[4*q+2] = fmaf(g1, a.z, acc1[4*q+2]);
                acc1[4*q+3] = fmaf(g1, a.w, acc1[4*q+3]);
            }
        }
    }
    float4* y0 = (float4*)(out + (((long)n*C_ + o0)*T_ + t)*VP_);
    float4* y1 = (float4*)(out + (((long)n*C_ + o1)*T_ + t)*VP_);
    #pragma unroll
    for (int q = 0; q < 5; q++) {
        y0[q] = make_float4(acc0[4*q], acc0[4*q+1], acc0[4*q+2], acc0[4*q+3]);
        y1[q] = make_float4(acc1[4*q], acc1[4*q+1], acc1[4*q+2], acc1[4*q+3]);
    }
}

// ---------- K8: BN batch stats -> fused scale/shift ----------
__global__ __launch_bounds__(256) void k_bnstat(const float* __restrict__ y,
    const float* __restrict__ gamma, const float* __restrict__ beta,
    float* __restrict__ scale, float* __restrict__ shift)
{
    int o = blockIdx.x, tid = threadIdx.x;
    float sum = 0.f, sq = 0.f;
    for (int n = 0; n < N_; n++) {
        const float4* p = (const float4*)(y + (long)(n*C_ + o)*T_*VP_);
        for (int idx = tid; idx < T_*VP_/4; idx += 256) {
            float4 v = p[idx];
            sum += v.x + v.y + v.z + v.w;
            sq  += v.x*v.x + v.y*v.y + v.z*v.z + v.w*v.w;
        }
    }
    __shared__ float s1[256], s2[256];
    s1[tid] = sum; s2[tid] = sq;
    __syncthreads();
    for (int off = 128; off > 0; off >>= 1) {
        if (tid < off) { s1[tid] += s1[tid+off]; s2[tid] += s2[tid+off]; }
        __syncthreads();
    }
    if (tid == 0) {
        const float M = (float)(N_*T_*VP_);
        float mean = s1[0] / M;
        float var  = s2[0] / M - mean*mean;
        float g = gamma[o] * rsqrtf(var + 1e-5f);
        scale[o] = g;
        shift[o] = beta[o] - mean*g;
    }
}

// ---------- K9: out = relu(y*scale + shift + xp) ----------
__global__ void k_final(float* __restrict__ out, const u16* __restrict__ xp,
    const float* __restrict__ scale, const float* __restrict__ shift)
{
    const long total4 = (long)N_*C_*T_*VP_/4;
    long stride = (long)gridDim.x * blockDim.x;
    for (long i4 = (long)blockIdx.x*blockDim.x + threadIdx.x; i4 < total4; i4 += stride) {
        int c = (int)((i4 / (T_*VP_/4)) & (C_-1));
        float4 v = ((const float4*)out)[i4];
        uint2 xu = ((const uint2*)xp)[i4];
        float sc = scale[c], sh = shift[c];
        float x0 = __uint_as_float(xu.x << 16);
        float x1 = __uint_as_float(xu.x & 0xFFFF0000u);
        float x2 = __uint_as_float(xu.y << 16);
        float x3 = __uint_as_float(xu.y & 0xFFFF0000u);
        v.x = fmaxf(fmaf(v.x, sc, sh) + x0, 0.f);
        v.y = fmaxf(fmaf(v.y, sc, sh) + x1, 0.f);
        v.z = fmaxf(fmaf(v.z, sc, sh) + x2, 0.f);
        v.w = fmaxf(fmaf(v.w, sc, sh) + x3, 0.f);
        ((float4*)out)[i4] = v;
    }
}

extern "C" void kernel_launch(void* const* d_in, const int* in_sizes, int n_in,
                              void* d_out, int out_size, void* d_ws, size_t ws_size,
                              hipStream_t stream)
{
    const float* x     = (const float*)d_in[0];
    const float* PA    = (const float*)d_in[1];
    const float* A_fix = (const float*)d_in[2];
    const float* w_e   = (const float*)d_in[3];
    const float* b_e   = (const float*)d_in[4];
    const float* wa    = (const float*)d_in[5];
    const float* ba    = (const float*)d_in[6];
    const float* wb    = (const float*)d_in[7];
    const float* bb    = (const float*)d_in[8];
    const float* wd    = (const float*)d_in[9];
    const float* bd    = (const float*)d_in[10];
    const float* gamma = (const float*)d_in[11];
    const float* beta  = (const float*)d_in[12];
    float* out = (float*)d_out;

    char* ws = (char*)d_ws;
    const size_t FAFBG_B = (size_t)N_*WROWS*M_*2;      // 188,743,680
    const size_t XP_B    = (size_t)N_*C_*T_*VP_*2;     //  41,943,040
    const size_t WB_B    = (size_t)WROWS*C_*2;         //     589,824
    const size_t BIAS_B  = (size_t)WROWS*4;            //       4,608
    const size_t SC_B    = (size_t)N_*S_*VP_*VP_*4;    //      76,800
    u16*   fafbg = (u16*)(ws);
    u16*   xp    = (u16*)(ws + FAFBG_B);
    u16*   xpT   = (u16*)(ws + FAFBG_B + XP_B);
    u16*   Wb    = (u16*)(ws + FAFBG_B + 2*XP_B);
    float* biasv = (float*)(ws + FAFBG_B + 2*XP_B + WB_B);
    float* scores= (float*)(ws + FAFBG_B + 2*XP_B + WB_B + BIAS_B);
    float* att   = (float*)(ws + FAFBG_B + 2*XP_B + WB_B + BIAS_B + SC_B);
    float* scale = (float*)(ws + FAFBG_B + 2*XP_B + WB_B + BIAS_B + 2*SC_B);
    float* shift = scale + C_;

    k_conv_e<<<4096, 256, 0, stream>>>(x, w_e, b_e, xp);
    k_packW<<<WROWS, 256, 0, stream>>>(wa, wb, wd, ba, bb, Wb, biasv);
    k_tr<<<5120, 256, 0, stream>>>(xp, xpT);
    k_gemm<<<5760, 256, 0, stream>>>(Wb, xpT, biasv, fafbg);
    hipMemsetAsync(scores, 0, SC_B, stream);
    k_scores_red<<<384, 256, 0, stream>>>(fafbg, scores);
    k_att<<<N_*S_, 32, 0, stream>>>(scores, PA, A_fix, att);
    k_comb<<<4096, 128, 0, stream>>>(fafbg, att, bd, out);
    k_bnstat<<<C_, 256, 0, stream>>>(out, gamma, beta, scale, shift);
    k_final<<<2048, 256, 0, stream>>>(out, xp, scale, shift);
}

// Round 5
// 550.284 us; speedup vs baseline: 2.7658x; 1.5054x over previous
//
#include <hip/hip_runtime.h>

typedef unsigned short u16;
typedef unsigned int u32;
typedef float __attribute__((ext_vector_type(4))) f32x4;
typedef short __attribute__((ext_vector_type(8))) s16x8;

#define N_ 16
#define C_ 256
#define T_ 256
#define V_ 25
#define VP_ 20
#define S_ 3
#define IC_ 64
#define M_ (T_*VP_)      // 5120 spatial per n
#define WROWS 1152       // 192 fa + 192 fb + 768 g rows

__device__ __forceinline__ u16 f2bf(float f) {
    u32 u = __float_as_uint(f);
    u32 r = (u + 0x7FFFu + ((u >> 16) & 1u)) >> 16;
    return (u16)r;
}
__device__ __forceinline__ float bf2f(u16 h) {
    return __uint_as_float(((u32)h) << 16);
}

// ---------- K1: xp_bf16[n][c][t][v] = x @ w_e + b_e ----------
__global__ __launch_bounds__(256) void k_conv_e(const float* __restrict__ x,
    const float* __restrict__ w_e, const float* __restrict__ b_e, u16* __restrict__ xp)
{
    __shared__ __align__(16) float sw[V_*VP_];
    __shared__ float sb[VP_];
    int tid = threadIdx.x;
    for (int i = tid; i < V_*VP_; i += 256) sw[i] = w_e[i];
    if (tid < VP_) sb[tid] = b_e[tid];
    __syncthreads();
    long row = (long)blockIdx.x*256 + tid;     // (n,c,t) row
    const float* xr = x + row*V_;
    float acc[VP_];
    #pragma unroll
    for (int u = 0; u < VP_; u++) acc[u] = sb[u];
    #pragma unroll
    for (int v = 0; v < V_; v++) {
        float xv = xr[v];
        const float4* w4 = (const float4*)&sw[v*VP_];
        #pragma unroll
        for (int q = 0; q < 5; q++) {
            float4 w = w4[q];
            acc[4*q+0] = fmaf(xv, w.x, acc[4*q+0]);
            acc[4*q+1] = fmaf(xv, w.y, acc[4*q+1]);
            acc[4*q+2] = fmaf(xv, w.z, acc[4*q+2]);
            acc[4*q+3] = fmaf(xv, w.w, acc[4*q+3]);
        }
    }
    u32 ub[10];
    #pragma unroll
    for (int q = 0; q < 10; q++)
        ub[q] = (u32)f2bf(acc[2*q]) | ((u32)f2bf(acc[2*q+1]) << 16);
    uint2* o2 = (uint2*)(xp + row*VP_);
    #pragma unroll
    for (int q = 0; q < 5; q++) o2[q] = make_uint2(ub[2*q], ub[2*q+1]);
}

// ---------- K2: pack weights [wa;wb;wd] -> bf16 [1152][256] + bias vector ----------
__global__ void k_packW(const float* __restrict__ wa, const float* __restrict__ wb,
    const float* __restrict__ wd, const float* __restrict__ ba, const float* __restrict__ bb,
    u16* __restrict__ Wb, float* __restrict__ biasv)
{
    int row = blockIdx.x, c = threadIdx.x;
    const float* src = (row < 192) ? (wa + (long)row*C_)
                     : (row < 384) ? (wb + (long)(row-192)*C_)
                                   : (wd + (long)(row-384)*C_);
    Wb[(long)row*C_ + c] = f2bf(src[c]);
    if (c == 0) biasv[row] = (row < 192) ? ba[row] : ((row < 384) ? bb[row-192] : 0.f);
}

// ---------- K3: xpT[n][m][c] = xp[n][c][m], 64x64 tiles ----------
__global__ __launch_bounds__(256) void k_tr(const u16* __restrict__ xp, u16* __restrict__ xpT)
{
    __shared__ __align__(16) u16 tile[64*68];
    int bid = blockIdx.x;
    int cb = bid & 3, mb = (bid >> 2) % 80, n = bid / 320;
    int c0 = cb*64, m0 = mb*64;
    int tid = threadIdx.x;
    int rr = tid >> 4;            // 0..15
    int q4 = (tid & 15) * 4;      // 0..60
    const u16* xin = xp + (long)n*C_*M_;
    #pragma unroll
    for (int p = 0; p < 4; p++) {
        int c = p*16 + rr;
        uint2 rv = *(const uint2*)(xin + (long)(c0+c)*M_ + m0 + q4);
        *(uint2*)(&tile[c*68 + q4]) = rv;
    }
    __syncthreads();
    u16* xout = xpT + (long)n*M_*C_;
    #pragma unroll
    for (int p = 0; p < 4; p++) {
        int m = p*16 + rr;
        u32 u0 = (u32)tile[(q4+0)*68 + m] | ((u32)tile[(q4+1)*68 + m] << 16);
        u32 u1 = (u32)tile[(q4+2)*68 + m] | ((u32)tile[(q4+3)*68 + m] << 16);
        *(uint2*)(xout + (long)(m0+m)*C_ + c0 + q4) = make_uint2(u0, u1);
    }
}

// ---------- K4: fafbg[n][1152][5120] = Wb @ xp  (MFMA, 128x128 tile, BK=64) ----------
__global__ __launch_bounds__(256) void k_gemm(const u16* __restrict__ Wb,
    const u16* __restrict__ xpT, const float* __restrict__ biasv, u16* __restrict__ out)
{
    __shared__ __align__(16) short smem[128*64 + 128*64];   // 32 KB
    short* As = smem;
    short* Bs = smem + 128*64;
    int bid = blockIdx.x;
    int nb = bid % 40;
    int mb = (bid / 40) % 9;
    int n  = bid / 360;
    int tid = threadIdx.x;
    int wid = tid >> 6, lane = tid & 63;
    int wr = wid >> 1, wc = wid & 1;

    float biasr[4][4];
    {
        int rbase = mb*128 + wr*64 + ((lane >> 4) << 2);
        #pragma unroll
        for (int m = 0; m < 4; m++)
            #pragma unroll
            for (int r = 0; r < 4; r++)
                biasr[m][r] = biasv[rbase + m*16 + r];
    }
    const u16* Ag = Wb + (long)mb*128*C_;
    const u16* Bg = xpT + ((long)n*M_ + (long)nb*128)*C_;

    f32x4 acc[4][4];
    #pragma unroll
    for (int m = 0; m < 4; m++)
        #pragma unroll
        for (int nf = 0; nf < 4; nf++)
            acc[m][nf] = f32x4{0.f, 0.f, 0.f, 0.f};

    auto stage = [&](int k0) {
        #pragma unroll
        for (int j = 0; j < 4; j++) {
            int L = j*256 + wid*64 + lane;
            int row = L >> 3, ko = (L & 7) * 8;
            __builtin_amdgcn_global_load_lds(
                (const unsigned int*)(Ag + (long)row*C_ + k0 + ko),
                (unsigned int*)(As + (j*256 + wid*64)*8), 16, 0, 0);
            __builtin_amdgcn_global_load_lds(
                (const unsigned int*)(Bg + (long)row*C_ + k0 + ko),
                (unsigned int*)(Bs + (j*256 + wid*64)*8), 16, 0, 0);
        }
    };

    stage(0);
    __syncthreads();
    for (int kt = 0; kt < 4; kt++) {
        #pragma unroll
        for (int ks = 0; ks < 2; ks++) {
            s16x8 af[4], bg[4];
            #pragma unroll
            for (int m = 0; m < 4; m++)
                af[m] = *(const s16x8*)(As + (wr*64 + m*16 + (lane & 15))*64 + ks*32 + ((lane >> 4) << 3));
            #pragma unroll
            for (int nf = 0; nf < 4; nf++)
                bg[nf] = *(const s16x8*)(Bs + (wc*64 + nf*16 + (lane & 15))*64 + ks*32 + ((lane >> 4) << 3));
            #pragma unroll
            for (int m = 0; m < 4; m++)
                #pragma unroll
                for (int nf = 0; nf < 4; nf++)
                    acc[m][nf] = __builtin_amdgcn_mfma_f32_16x16x32_bf16(af[m], bg[nf], acc[m][nf], 0, 0, 0);
        }
        if (kt < 3) {
            __syncthreads();
            stage((kt+1)*64);
            __syncthreads();
        }
    }
    __syncthreads();
    // epilogue: frags -> LDS bf16 C-tile -> coalesced global store
    u16* Cs = (u16*)smem;
    #pragma unroll
    for (int m = 0; m < 4; m++)
        #pragma unroll
        for (int nf = 0; nf < 4; nf++)
            #pragma unroll
            for (int r = 0; r < 4; r++) {
                int row = wr*64 + m*16 + ((lane >> 4) << 2) + r;
                int col = wc*64 + nf*16 + (lane & 15);
                Cs[row*128 + col] = f2bf(acc[m][nf][r] + biasr[m][r]);
            }
    __syncthreads();
    u16* og = out + ((long)n*WROWS + (long)mb*128)*M_ + (long)nb*128;
    #pragma unroll
    for (int j = 0; j < 8; j++) {
        int idx = j*256 + tid;
        int row = idx >> 4, c8 = (idx & 15) * 8;
        uint4 v = *(const uint4*)(Cs + row*128 + c8);
        *(uint4*)(og + (long)row*M_ + c8) = v;
    }
}

// ---------- K5: scores[n][s][v][u] = sum_{i,t} fa[i,t,v]*fb[i,t,u] via MFMA ----------
// grid: n*(S_*32) + s*32 + kc ; each block covers i in {2kc,2kc+1}, all t.
__global__ __launch_bounds__(256) void k_scores_mfma(const u16* __restrict__ fafbg,
    float* __restrict__ scores)
{
    __shared__ __align__(16) u16 sfa[2*256*VP_];   // [i2][t][v], 20480 B
    __shared__ __align__(16) u16 sfb[2*256*VP_];
    __shared__ float ssc[VP_*VP_];
    int bid = blockIdx.x;
    int kc = bid & 31;
    int s  = (bid >> 5) % 3;
    int n  = bid / 96;
    int tid = threadIdx.x;
    int w = tid >> 6, lane = tid & 63;

    // stage 2 contiguous fa rows + 2 fb rows (coalesced uint4)
    const uint4* fa4 = (const uint4*)(fafbg + ((long)n*WROWS + s*IC_ + 2*kc)*M_);
    const uint4* fb4 = (const uint4*)(fafbg + ((long)n*WROWS + 192 + s*IC_ + 2*kc)*M_);
    uint4* da = (uint4*)sfa;
    uint4* db = (uint4*)sfb;
    #pragma unroll
    for (int j = 0; j < 5; j++) {
        da[j*256 + tid] = fa4[j*256 + tid];
        db[j*256 + tid] = fb4[j*256 + tid];
    }
    for (int i = tid; i < VP_*VP_; i += 256) ssc[i] = 0.f;
    __syncthreads();

    int iw = w >> 1;                 // local i (0/1)
    int t0 = (w & 1) * 128;          // wave's t-range
    const u16* pa = sfa + iw*256*VP_;
    const u16* pb = sfb + iw*256*VP_;
    int vrow = lane & 15;
    int kg = lane >> 4;              // 0..3
    f32x4 acc[2][2];
    #pragma unroll
    for (int m = 0; m < 2; m++)
        #pragma unroll
        for (int nn = 0; nn < 2; nn++)
            acc[m][nn] = f32x4{0.f, 0.f, 0.f, 0.f};

    for (int step = 0; step < 4; step++) {
        int tb = t0 + step*32 + kg*8;          // 8 consecutive t for this lane
        s16x8 af0, af1, bg0, bg1;
        #pragma unroll
        for (int j = 0; j < 8; j++) {
            int t = tb + j;
            af0[j] = (short)pa[t*VP_ + vrow];
            bg0[j] = (short)pb[t*VP_ + vrow];
            af1[j] = (vrow < 4) ? (short)pa[t*VP_ + 16 + vrow] : (short)0;
            bg1[j] = (vrow < 4) ? (short)pb[t*VP_ + 16 + vrow] : (short)0;
        }
        acc[0][0] = __builtin_amdgcn_mfma_f32_16x16x32_bf16(af0, bg0, acc[0][0], 0, 0, 0);
        acc[0][1] = __builtin_amdgcn_mfma_f32_16x16x32_bf16(af0, bg1, acc[0][1], 0, 0, 0);
        acc[1][0] = __builtin_amdgcn_mfma_f32_16x16x32_bf16(af1, bg0, acc[1][0], 0, 0, 0);
        acc[1][1] = __builtin_amdgcn_mfma_f32_16x16x32_bf16(af1, bg1, acc[1][1], 0, 0, 0);
    }
    // C layout: row(v-part) = (lane>>4)*4 + r, col(u-part) = lane&15
    #pragma unroll
    for (int m = 0; m < 2; m++)
        #pragma unroll
        for (int nn = 0; nn < 2; nn++)
            #pragma unroll
            for (int r = 0; r < 4; r++) {
                int v = m*16 + kg*4 + r;
                int u = nn*16 + vrow;
                if (v < VP_ && u < VP_)
                    atomicAdd(&ssc[v*VP_ + u], acc[m][nn][r]);
            }
    __syncthreads();
    float* scb = scores + (long)(n*S_ + s)*VP_*VP_;
    for (int i = tid; i < VP_*VP_; i += 256)
        atomicAdd(&scb[i], ssc[i]);
}

// ---------- K6: att = softmax_v(scores/(IC*T)) + (A_fix + PA) ----------
__global__ void k_att(const float* __restrict__ scores, const float* __restrict__ PA,
    const float* __restrict__ A_fix, float* __restrict__ att)
{
    int ns = blockIdx.x;
    int s = ns - (ns / S_)*S_;
    int u = threadIdx.x;
    if (u >= VP_) return;
    const float* sc = scores + (long)ns*VP_*VP_;
    const float inv = 1.0f / (IC_*T_);
    float m = -1e30f;
    for (int v = 0; v < VP_; v++) m = fmaxf(m, sc[v*VP_+u]);
    m *= inv;
    float e[VP_]; float sum = 0.f;
    for (int v = 0; v < VP_; v++) { float t = __expf(sc[v*VP_+u]*inv - m); e[v] = t; sum += t; }
    float r = 1.0f / sum;
    const float* Ab = A_fix + s*VP_*VP_;
    const float* Pb = PA    + s*VP_*VP_;
    float* ob = att + (long)ns*VP_*VP_;
    for (int v = 0; v < VP_; v++) ob[v*VP_+u] = e[v]*r + Ab[v*VP_+u] + Pb[v*VP_+u];
}

// ---------- K7: y[n][o][t][u] = sum_{s,v} g[s,o,t,v]*att[s,v,u] + bd_sum ----------
__global__ __launch_bounds__(128) void k_comb(const u16* __restrict__ fafbg,
    const float* __restrict__ att, const float* __restrict__ bd, float* __restrict__ out)
{
    __shared__ __align__(16) u16 gsh[S_*C_*VP_];       // 30720 B
    __shared__ __align__(16) float attsh[S_*VP_*VP_];  // 4800 B
    int nt = blockIdx.x, n = nt >> 8, t = nt & 255;
    int tid = threadIdx.x;
    for (int i = tid; i < S_*VP_*VP_; i += 128) attsh[i] = att[(long)n*S_*VP_*VP_ + i];
    const u32* gbase = (const u32*)fafbg;
    u32* gsh32 = (u32*)gsh;
    for (int j = 0; j < 60; j++) {
        int idx = j*128 + tid;
        int r = idx / 10, d = idx - r*10;
        gsh32[idx] = gbase[(long)(n*WROWS + 384 + r)*2560 + t*10 + d];
    }
    __syncthreads();
    int o0 = tid, o1 = tid + 128;
    float acc0[VP_], acc1[VP_];
    {
        float bs0 = bd[o0] + bd[C_+o0] + bd[2*C_+o0];
        float bs1 = bd[o1] + bd[C_+o1] + bd[2*C_+o1];
        #pragma unroll
        for (int u = 0; u < VP_; u++) { acc0[u] = bs0; acc1[u] = bs1; }
    }
    for (int s = 0; s < S_; s++) {
        #pragma unroll
        for (int v = 0; v < VP_; v++) {
            const float4* ar = (const float4*)&attsh[(s*VP_+v)*VP_];
            float g0 = bf2f(gsh[(s*C_+o0)*VP_ + v]);
            float g1 = bf2f(gsh[(s*C_+o1)*VP_ + v]);
            #pragma unroll
            for (int q = 0; q < 5; q++) {
                float4 a = ar[q];
                acc0[4*q+0] = fmaf(g0, a.x, acc0[4*q+0]);
                acc0[4*q+1] = fmaf(g0, a.y, acc0[4*q+1]);
                acc0[4*q+2] = fmaf(g0, a.z, acc0[4*q+2]);
                acc0[4*q+3] = fmaf(g0, a.w, acc0[4*q+3]);
                acc1[4*q+0] = fmaf(g1, a.x, acc1[4*q+0]);
                acc1[4*q+1] = fmaf(g1, a.y, acc1[4*q+1]);
                acc1[4*q+2] = fmaf(g1, a.z, acc1[4*q+2]);
                acc1[4*q+3] = fmaf(g1, a.w, acc1[4*q+3]);
            }
        }
    }
    float4* y0 = (float4*)(out + (((long)n*C_ + o0)*T_ + t)*VP_);
    float4* y1 = (float4*)(out + (((long)n*C_ + o1)*T_ + t)*VP_);
    #pragma unroll
    for (int q = 0; q < 5; q++) {
        y0[q] = make_float4(acc0[4*q], acc0[4*q+1], acc0[4*q+2], acc0[4*q+3]);
        y1[q] = make_float4(acc1[4*q], acc1[4*q+1], acc1[4*q+2], acc1[4*q+3]);
    }
}

// ---------- K8: BN batch stats -> fused scale/shift ----------
__global__ __launch_bounds__(256) void k_bnstat(const float* __restrict__ y,
    const float* __restrict__ gamma, const float* __restrict__ beta,
    float* __restrict__ scale, float* __restrict__ shift)
{
    int o = blockIdx.x, tid = threadIdx.x;
    float sum = 0.f, sq = 0.f;
    for (int n = 0; n < N_; n++) {
        const float4* p = (const float4*)(y + (long)(n*C_ + o)*T_*VP_);
        for (int idx = tid; idx < T_*VP_/4; idx += 256) {
            float4 v = p[idx];
            sum += v.x + v.y + v.z + v.w;
            sq  += v.x*v.x + v.y*v.y + v.z*v.z + v.w*v.w;
        }
    }
    __shared__ float s1[256], s2[256];
    s1[tid] = sum; s2[tid] = sq;
    __syncthreads();
    for (int off = 128; off > 0; off >>= 1) {
        if (tid < off) { s1[tid] += s1[tid+off]; s2[tid] += s2[tid+off]; }
        __syncthreads();
    }
    if (tid == 0) {
        const float M = (float)(N_*T_*VP_);
        float mean = s1[0] / M;
        float var  = s2[0] / M - mean*mean;
        float g = gamma[o] * rsqrtf(var + 1e-5f);
        scale[o] = g;
        shift[o] = beta[o] - mean*g;
    }
}

// ---------- K9: out = relu(y*scale + shift + xp) ----------
__global__ void k_final(float* __restrict__ out, const u16* __restrict__ xp,
    const float* __restrict__ scale, const float* __restrict__ shift)
{
    const long total4 = (long)N_*C_*T_*VP_/4;
    long stride = (long)gridDim.x * blockDim.x;
    for (long i4 = (long)blockIdx.x*blockDim.x + threadIdx.x; i4 < total4; i4 += stride) {
        int c = (int)((i4 / (T_*VP_/4)) & (C_-1));
        float4 v = ((const float4*)out)[i4];
        uint2 xu = ((const uint2*)xp)[i4];
        float sc = scale[c], sh = shift[c];
        float x0 = __uint_as_float(xu.x << 16);
        float x1 = __uint_as_float(xu.x & 0xFFFF0000u);
        float x2 = __uint_as_float(xu.y << 16);
        float x3 = __uint_as_float(xu.y & 0xFFFF0000u);
        v.x = fmaxf(fmaf(v.x, sc, sh) + x0, 0.f);
        v.y = fmaxf(fmaf(v.y, sc, sh) + x1, 0.f);
        v.z = fmaxf(fmaf(v.z, sc, sh) + x2, 0.f);
        v.w = fmaxf(fmaf(v.w, sc, sh) + x3, 0.f);
        ((float4*)out)[i4] = v;
    }
}

extern "C" void kernel_launch(void* const* d_in, const int* in_sizes, int n_in,
                              void* d_out, int out_size, void* d_ws, size_t ws_size,
                              hipStream_t stream)
{
    const float* x     = (const float*)d_in[0];
    const float* PA    = (const float*)d_in[1];
    const float* A_fix = (const float*)d_in[2];
    const float* w_e   = (const float*)d_in[3];
    const float* b_e   = (const float*)d_in[4];
    const float* wa    = (const float*)d_in[5];
    const float* ba    = (const float*)d_in[6];
    const float* wb    = (const float*)d_in[7];
    const float* bb    = (const float*)d_in[8];
    const float* wd    = (const float*)d_in[9];
    const float* bd    = (const float*)d_in[10];
    const float* gamma = (const float*)d_in[11];
    const float* beta  = (const float*)d_in[12];
    float* out = (float*)d_out;

    char* ws = (char*)d_ws;
    const size_t FAFBG_B = (size_t)N_*WROWS*M_*2;      // 188,743,680
    const size_t XP_B    = (size_t)N_*C_*T_*VP_*2;     //  41,943,040
    const size_t WB_B    = (size_t)WROWS*C_*2;         //     589,824
    const size_t BIAS_B  = (size_t)WROWS*4;            //       4,608
    const size_t SC_B    = (size_t)N_*S_*VP_*VP_*4;    //      76,800
    u16*   fafbg = (u16*)(ws);
    u16*   xp    = (u16*)(ws + FAFBG_B);
    u16*   xpT   = (u16*)(ws + FAFBG_B + XP_B);
    u16*   Wb    = (u16*)(ws + FAFBG_B + 2*XP_B);
    float* biasv = (float*)(ws + FAFBG_B + 2*XP_B + WB_B);
    float* scores= (float*)(ws + FAFBG_B + 2*XP_B + WB_B + BIAS_B);
    float* att   = (float*)(ws + FAFBG_B + 2*XP_B + WB_B + BIAS_B + SC_B);
    float* scale = (float*)(ws + FAFBG_B + 2*XP_B + WB_B + BIAS_B + 2*SC_B);
    float* shift = scale + C_;

    k_conv_e<<<4096, 256, 0, stream>>>(x, w_e, b_e, xp);
    k_packW<<<WROWS, 256, 0, stream>>>(wa, wb, wd, ba, bb, Wb, biasv);
    k_tr<<<5120, 256, 0, stream>>>(xp, xpT);
    k_gemm<<<5760, 256, 0, stream>>>(Wb, xpT, biasv, fafbg);
    hipMemsetAsync(scores, 0, SC_B, stream);
    k_scores_mfma<<<N_*S_*32, 256, 0, stream>>>(fafbg, scores);
    k_att<<<N_*S_, 32, 0, stream>>>(scores, PA, A_fix, att);
    k_comb<<<4096, 128, 0, stream>>>(fafbg, att, bd, out);
    k_bnstat<<<C_, 256, 0, stream>>>(out, gamma, beta, scale, shift);
    k_final<<<2048, 256, 0, stream>>>(out, xp, scale, shift);
}

// Round 8
// 443.959 us; speedup vs baseline: 3.4282x; 1.2395x over previous
//
#include <hip/hip_runtime.h>

typedef unsigned short u16;
typedef unsigned int u32;
typedef float __attribute__((ext_vector_type(4))) f32x4;
typedef short __attribute__((ext_vector_type(8))) s16x8;

#define N_ 16
#define C_ 256
#define T_ 256
#define V_ 25
#define VP_ 20
#define S_ 3
#define IC_ 64
#define M_ (T_*VP_)      // 5120 spatial per n
#define WROWS 1152       // 192 fa + 192 fb + 768 g rows

__device__ __forceinline__ u16 f2bf(float f) {
    u32 u = __float_as_uint(f);
    u32 r = (u + 0x7FFFu + ((u >> 16) & 1u)) >> 16;
    return (u16)r;
}
__device__ __forceinline__ float bf2f(u16 h) {
    return __uint_as_float(((u32)h) << 16);
}

// ---------- K1: xp_bf16[n][c][t][v] = x @ w_e + b_e ----------
__global__ __launch_bounds__(256) void k_conv_e(const float* __restrict__ x,
    const float* __restrict__ w_e, const float* __restrict__ b_e, u16* __restrict__ xp)
{
    __shared__ __align__(16) float sw[V_*VP_];
    __shared__ float sb[VP_];
    int tid = threadIdx.x;
    for (int i = tid; i < V_*VP_; i += 256) sw[i] = w_e[i];
    if (tid < VP_) sb[tid] = b_e[tid];
    __syncthreads();
    long row = (long)blockIdx.x*256 + tid;     // (n,c,t) row
    const float* xr = x + row*V_;
    float acc[VP_];
    #pragma unroll
    for (int u = 0; u < VP_; u++) acc[u] = sb[u];
    #pragma unroll
    for (int v = 0; v < V_; v++) {
        float xv = xr[v];
        const float4* w4 = (const float4*)&sw[v*VP_];
        #pragma unroll
        for (int q = 0; q < 5; q++) {
            float4 w = w4[q];
            acc[4*q+0] = fmaf(xv, w.x, acc[4*q+0]);
            acc[4*q+1] = fmaf(xv, w.y, acc[4*q+1]);
            acc[4*q+2] = fmaf(xv, w.z, acc[4*q+2]);
            acc[4*q+3] = fmaf(xv, w.w, acc[4*q+3]);
        }
    }
    u32 ub[10];
    #pragma unroll
    for (int q = 0; q < 10; q++)
        ub[q] = (u32)f2bf(acc[2*q]) | ((u32)f2bf(acc[2*q+1]) << 16);
    uint2* o2 = (uint2*)(xp + row*VP_);
    #pragma unroll
    for (int q = 0; q < 5; q++) o2[q] = make_uint2(ub[2*q], ub[2*q+1]);
}

// ---------- K2: pack weights [wa;wb;wd] -> bf16 [1152][256] + bias vector ----------
__global__ void k_packW(const float* __restrict__ wa, const float* __restrict__ wb,
    const float* __restrict__ wd, const float* __restrict__ ba, const float* __restrict__ bb,
    u16* __restrict__ Wb, float* __restrict__ biasv)
{
    int row = blockIdx.x, c = threadIdx.x;
    const float* src = (row < 192) ? (wa + (long)row*C_)
                     : (row < 384) ? (wb + (long)(row-192)*C_)
                                   : (wd + (long)(row-384)*C_);
    Wb[(long)row*C_ + c] = f2bf(src[c]);
    if (c == 0) biasv[row] = (row < 192) ? ba[row] : ((row < 384) ? bb[row-192] : 0.f);
}

// ---------- K3: xpT[n][m][c] = xp[n][c][m], 64x64 tiles ----------
__global__ __launch_bounds__(256) void k_tr(const u16* __restrict__ xp, u16* __restrict__ xpT)
{
    __shared__ __align__(16) u16 tile[64*68];
    int bid = blockIdx.x;
    int cb = bid & 3, mb = (bid >> 2) % 80, n = bid / 320;
    int c0 = cb*64, m0 = mb*64;
    int tid = threadIdx.x;
    int rr = tid >> 4;            // 0..15
    int q4 = (tid & 15) * 4;      // 0..60
    const u16* xin = xp + (long)n*C_*M_;
    #pragma unroll
    for (int p = 0; p < 4; p++) {
        int c = p*16 + rr;
        uint2 rv = *(const uint2*)(xin + (long)(c0+c)*M_ + m0 + q4);
        *(uint2*)(&tile[c*68 + q4]) = rv;
    }
    __syncthreads();
    u16* xout = xpT + (long)n*M_*C_;
    #pragma unroll
    for (int p = 0; p < 4; p++) {
        int m = p*16 + rr;
        u32 u0 = (u32)tile[(q4+0)*68 + m] | ((u32)tile[(q4+1)*68 + m] << 16);
        u32 u1 = (u32)tile[(q4+2)*68 + m] | ((u32)tile[(q4+3)*68 + m] << 16);
        *(uint2*)(xout + (long)(m0+m)*C_ + c0 + q4) = make_uint2(u0, u1);
    }
}

// ---------- K4: fafbg[n][1152][5120] = Wb @ xp  (MFMA, 128x128 tile, BK=64) ----------
__global__ __launch_bounds__(256) void k_gemm(const u16* __restrict__ Wb,
    const u16* __restrict__ xpT, const float* __restrict__ biasv, u16* __restrict__ out)
{
    __shared__ __align__(16) short smem[128*64 + 128*64];   // 32 KB
    short* As = smem;
    short* Bs = smem + 128*64;
    int bid = blockIdx.x;
    int nb = bid % 40;
    int mb = (bid / 40) % 9;
    int n  = bid / 360;
    int tid = threadIdx.x;
    int wid = tid >> 6, lane = tid & 63;
    int wr = wid >> 1, wc = wid & 1;

    float biasr[4][4];
    {
        int rbase = mb*128 + wr*64 + ((lane >> 4) << 2);
        #pragma unroll
        for (int m = 0; m < 4; m++)
            #pragma unroll
            for (int r = 0; r < 4; r++)
                biasr[m][r] = biasv[rbase + m*16 + r];
    }
    const u16* Ag = Wb + (long)mb*128*C_;
    const u16* Bg = xpT + ((long)n*M_ + (long)nb*128)*C_;

    f32x4 acc[4][4];
    #pragma unroll
    for (int m = 0; m < 4; m++)
        #pragma unroll
        for (int nf = 0; nf < 4; nf++)
            acc[m][nf] = f32x4{0.f, 0.f, 0.f, 0.f};

    auto stage = [&](int k0) {
        #pragma unroll
        for (int j = 0; j < 4; j++) {
            int L = j*256 + wid*64 + lane;
            int row = L >> 3, ko = (L & 7) * 8;
            __builtin_amdgcn_global_load_lds(
                (const unsigned int*)(Ag + (long)row*C_ + k0 + ko),
                (unsigned int*)(As + (j*256 + wid*64)*8), 16, 0, 0);
            __builtin_amdgcn_global_load_lds(
                (const unsigned int*)(Bg + (long)row*C_ + k0 + ko),
                (unsigned int*)(Bs + (j*256 + wid*64)*8), 16, 0, 0);
        }
    };

    stage(0);
    __syncthreads();
    for (int kt = 0; kt < 4; kt++) {
        #pragma unroll
        for (int ks = 0; ks < 2; ks++) {
            s16x8 af[4], bg[4];
            #pragma unroll
            for (int m = 0; m < 4; m++)
                af[m] = *(const s16x8*)(As + (wr*64 + m*16 + (lane & 15))*64 + ks*32 + ((lane >> 4) << 3));
            #pragma unroll
            for (int nf = 0; nf < 4; nf++)
                bg[nf] = *(const s16x8*)(Bs + (wc*64 + nf*16 + (lane & 15))*64 + ks*32 + ((lane >> 4) << 3));
            #pragma unroll
            for (int m = 0; m < 4; m++)
                #pragma unroll
                for (int nf = 0; nf < 4; nf++)
                    acc[m][nf] = __builtin_amdgcn_mfma_f32_16x16x32_bf16(af[m], bg[nf], acc[m][nf], 0, 0, 0);
        }
        if (kt < 3) {
            __syncthreads();
            stage((kt+1)*64);
            __syncthreads();
        }
    }
    __syncthreads();
    // epilogue: frags -> LDS bf16 C-tile -> coalesced global store
    u16* Cs = (u16*)smem;
    #pragma unroll
    for (int m = 0; m < 4; m++)
        #pragma unroll
        for (int nf = 0; nf < 4; nf++)
            #pragma unroll
            for (int r = 0; r < 4; r++) {
                int row = wr*64 + m*16 + ((lane >> 4) << 2) + r;
                int col = wc*64 + nf*16 + (lane & 15);
                Cs[row*128 + col] = f2bf(acc[m][nf][r] + biasr[m][r]);
            }
    __syncthreads();
    u16* og = out + ((long)n*WROWS + (long)mb*128)*M_ + (long)nb*128;
    #pragma unroll
    for (int j = 0; j < 8; j++) {
        int idx = j*256 + tid;
        int row = idx >> 4, c8 = (idx & 15) * 8;
        uint4 v = *(const uint4*)(Cs + row*128 + c8);
        *(uint4*)(og + (long)row*M_ + c8) = v;
    }
}

// ---------- K5: scores[n][s][v][u] = sum_{i,t} fa[i,t,v]*fb[i,t,u] via MFMA ----------
__global__ __launch_bounds__(256) void k_scores_mfma(const u16* __restrict__ fafbg,
    float* __restrict__ scores)
{
    __shared__ __align__(16) u16 sfa[2*256*VP_];   // [i2][t][v], 20480 B
    __shared__ __align__(16) u16 sfb[2*256*VP_];
    __shared__ float ssc[VP_*VP_];
    int bid = blockIdx.x;
    int kc = bid & 31;
    int s  = (bid >> 5) % 3;
    int n  = bid / 96;
    int tid = threadIdx.x;
    int w = tid >> 6, lane = tid & 63;

    const uint4* fa4 = (const uint4*)(fafbg + ((long)n*WROWS + s*IC_ + 2*kc)*M_);
    const uint4* fb4 = (const uint4*)(fafbg + ((long)n*WROWS + 192 + s*IC_ + 2*kc)*M_);
    uint4* da = (uint4*)sfa;
    uint4* db = (uint4*)sfb;
    #pragma unroll
    for (int j = 0; j < 5; j++) {
        da[j*256 + tid] = fa4[j*256 + tid];
        db[j*256 + tid] = fb4[j*256 + tid];
    }
    for (int i = tid; i < VP_*VP_; i += 256) ssc[i] = 0.f;
    __syncthreads();

    int iw = w >> 1;
    int t0 = (w & 1) * 128;
    const u16* pa = sfa + iw*256*VP_;
    const u16* pb = sfb + iw*256*VP_;
    int vrow = lane & 15;
    int kg = lane >> 4;
    f32x4 acc[2][2];
    #pragma unroll
    for (int m = 0; m < 2; m++)
        #pragma unroll
        for (int nn = 0; nn < 2; nn++)
            acc[m][nn] = f32x4{0.f, 0.f, 0.f, 0.f};

    for (int step = 0; step < 4; step++) {
        int tb = t0 + step*32 + kg*8;
        s16x8 af0, af1, bg0, bg1;
        #pragma unroll
        for (int j = 0; j < 8; j++) {
            int t = tb + j;
            af0[j] = (short)pa[t*VP_ + vrow];
            bg0[j] = (short)pb[t*VP_ + vrow];
            af1[j] = (vrow < 4) ? (short)pa[t*VP_ + 16 + vrow] : (short)0;
            bg1[j] = (vrow < 4) ? (short)pb[t*VP_ + 16 + vrow] : (short)0;
        }
        acc[0][0] = __builtin_amdgcn_mfma_f32_16x16x32_bf16(af0, bg0, acc[0][0], 0, 0, 0);
        acc[0][1] = __builtin_amdgcn_mfma_f32_16x16x32_bf16(af0, bg1, acc[0][1], 0, 0, 0);
        acc[1][0] = __builtin_amdgcn_mfma_f32_16x16x32_bf16(af1, bg0, acc[1][0], 0, 0, 0);
        acc[1][1] = __builtin_amdgcn_mfma_f32_16x16x32_bf16(af1, bg1, acc[1][1], 0, 0, 0);
    }
    #pragma unroll
    for (int m = 0; m < 2; m++)
        #pragma unroll
        for (int nn = 0; nn < 2; nn++)
            #pragma unroll
            for (int r = 0; r < 4; r++) {
                int v = m*16 + kg*4 + r;
                int u = nn*16 + vrow;
                if (v < VP_ && u < VP_)
                    atomicAdd(&ssc[v*VP_ + u], acc[m][nn][r]);
            }
    __syncthreads();
    float* scb = scores + (long)(n*S_ + s)*VP_*VP_;
    for (int i = tid; i < VP_*VP_; i += 256)
        atomicAdd(&scb[i], ssc[i]);
}

// ---------- K6: att = softmax_v(scores/(IC*T)) + (A_fix + PA) ----------
__global__ void k_att(const float* __restrict__ scores, const float* __restrict__ PA,
    const float* __restrict__ A_fix, float* __restrict__ att)
{
    int ns = blockIdx.x;
    int s = ns - (ns / S_)*S_;
    int u = threadIdx.x;
    if (u >= VP_) return;
    const float* sc = scores + (long)ns*VP_*VP_;
    const float inv = 1.0f / (IC_*T_);
    float m = -1e30f;
    for (int v = 0; v < VP_; v++) m = fmaxf(m, sc[v*VP_+u]);
    m *= inv;
    float e[VP_]; float sum = 0.f;
    for (int v = 0; v < VP_; v++) { float t = __expf(sc[v*VP_+u]*inv - m); e[v] = t; sum += t; }
    float r = 1.0f / sum;
    const float* Ab = A_fix + s*VP_*VP_;
    const float* Pb = PA    + s*VP_*VP_;
    float* ob = att + (long)ns*VP_*VP_;
    for (int v = 0; v < VP_; v++) ob[v*VP_+u] = e[v]*r + Ab[v*VP_+u] + Pb[v*VP_+u];
}

// ---------- K7: y[n][o][t][u] = sum_{s,v} g[n,s,o][t,v]*att[s,v,u] + bd_sum ----------
// block = (n,o): g rows fully contiguous, thread t reads its 40B coalesced.
__global__ __launch_bounds__(256) void k_comb(const u16* __restrict__ fafbg,
    const float* __restrict__ att, const float* __restrict__ bd, float* __restrict__ out)
{
    __shared__ __align__(16) float attsh[S_*VP_*VP_];
    int bid = blockIdx.x;
    int n = bid >> 8, o = bid & 255;
    int t = threadIdx.x;
    for (int i = t; i < S_*VP_*VP_; i += 256) attsh[i] = att[(long)n*S_*VP_*VP_ + i];
    __syncthreads();

    float acc[VP_];
    float bs = bd[o] + bd[C_+o] + bd[2*C_+o];
    #pragma unroll
    for (int u = 0; u < VP_; u++) acc[u] = bs;

    const u16* gbase = fafbg + ((long)n*WROWS + 384 + o)*M_ + t*VP_;
    #pragma unroll
    for (int s = 0; s < S_; s++) {
        const uint2* g2 = (const uint2*)(gbase + (long)s*C_*M_);
        uint2 gv[5];
        #pragma unroll
        for (int q = 0; q < 5; q++) gv[q] = g2[q];
        float gf[VP_];
        #pragma unroll
        for (int q = 0; q < 5; q++) {
            gf[4*q+0] = bf2f((u16)gv[q].x); gf[4*q+1] = bf2f((u16)(gv[q].x >> 16));
            gf[4*q+2] = bf2f((u16)gv[q].y); gf[4*q+3] = bf2f((u16)(gv[q].y >> 16));
        }
        #pragma unroll
        for (int v = 0; v < VP_; v++) {
            const float4* ar = (const float4*)&attsh[(s*VP_+v)*VP_];
            float g0 = gf[v];
            #pragma unroll
            for (int q = 0; q < 5; q++) {
                float4 a = ar[q];
                acc[4*q+0] = fmaf(g0, a.x, acc[4*q+0]);
                acc[4*q+1] = fmaf(g0, a.y, acc[4*q+1]);
                acc[4*q+2] = fmaf(g0, a.z, acc[4*q+2]);
                acc[4*q+3] = fmaf(g0, a.w, acc[4*q+3]);
            }
        }
    }
    float4* yb = (float4*)(out + (((long)n*C_ + o)*T_ + t)*VP_);
    #pragma unroll
    for (int q = 0; q < 5; q++)
        yb[q] = make_float4(acc[4*q], acc[4*q+1], acc[4*q+2], acc[4*q+3]);
}

// ---------- K8: BN batch stats -> fused scale/shift (R5-proven) ----------
__global__ __launch_bounds__(256) void k_bnstat(const float* __restrict__ y,
    const float* __restrict__ gamma, const float* __restrict__ beta,
    float* __restrict__ scale, float* __restrict__ shift)
{
    int o = blockIdx.x, tid = threadIdx.x;
    float sum = 0.f, sq = 0.f;
    for (int n = 0; n < N_; n++) {
        const float4* p = (const float4*)(y + (long)(n*C_ + o)*T_*VP_);
        for (int idx = tid; idx < T_*VP_/4; idx += 256) {
            float4 v = p[idx];
            sum += v.x + v.y + v.z + v.w;
            sq  += v.x*v.x + v.y*v.y + v.z*v.z + v.w*v.w;
        }
    }
    __shared__ float s1[256], s2[256];
    s1[tid] = sum; s2[tid] = sq;
    __syncthreads();
    for (int off = 128; off > 0; off >>= 1) {
        if (tid < off) { s1[tid] += s1[tid+off]; s2[tid] += s2[tid+off]; }
        __syncthreads();
    }
    if (tid == 0) {
        const float M = (float)(N_*T_*VP_);
        float mean = s1[0] / M;
        float var  = s2[0] / M - mean*mean;
        float g = gamma[o] * rsqrtf(var + 1e-5f);
        scale[o] = g;
        shift[o] = beta[o] - mean*g;
    }
}

// ---------- K9: out = relu(y*scale + shift + xp) ----------
__global__ void k_final(float* __restrict__ out, const u16* __restrict__ xp,
    const float* __restrict__ scale, const float* __restrict__ shift)
{
    const long total4 = (long)N_*C_*T_*VP_/4;
    long stride = (long)gridDim.x * blockDim.x;
    for (long i4 = (long)blockIdx.x*blockDim.x + threadIdx.x; i4 < total4; i4 += stride) {
        int c = (int)((i4 / (T_*VP_/4)) & (C_-1));
        float4 v = ((const float4*)out)[i4];
        uint2 xu = ((const uint2*)xp)[i4];
        float sc = scale[c], sh = shift[c];
        float x0 = __uint_as_float(xu.x << 16);
        float x1 = __uint_as_float(xu.x & 0xFFFF0000u);
        float x2 = __uint_as_float(xu.y << 16);
        float x3 = __uint_as_float(xu.y & 0xFFFF0000u);
        v.x = fmaxf(fmaf(v.x, sc, sh) + x0, 0.f);
        v.y = fmaxf(fmaf(v.y, sc, sh) + x1, 0.f);
        v.z = fmaxf(fmaf(v.z, sc, sh) + x2, 0.f);
        v.w = fmaxf(fmaf(v.w, sc, sh) + x3, 0.f);
        ((float4*)out)[i4] = v;
    }
}

extern "C" void kernel_launch(void* const* d_in, const int* in_sizes, int n_in,
                              void* d_out, int out_size, void* d_ws, size_t ws_size,
                              hipStream_t stream)
{
    const float* x     = (const float*)d_in[0];
    const float* PA    = (const float*)d_in[1];
    const float* A_fix = (const float*)d_in[2];
    const float* w_e   = (const float*)d_in[3];
    const float* b_e   = (const float*)d_in[4];
    const float* wa    = (const float*)d_in[5];
    const float* ba    = (const float*)d_in[6];
    const float* wb    = (const float*)d_in[7];
    const float* bb    = (const float*)d_in[8];
    const float* wd    = (const float*)d_in[9];
    const float* bd    = (const float*)d_in[10];
    const float* gamma = (const float*)d_in[11];
    const float* beta  = (const float*)d_in[12];
    float* out = (float*)d_out;

    char* ws = (char*)d_ws;
    const size_t FAFBG_B = (size_t)N_*WROWS*M_*2;      // 188,743,680
    const size_t XP_B    = (size_t)N_*C_*T_*VP_*2;     //  41,943,040
    const size_t WB_B    = (size_t)WROWS*C_*2;         //     589,824
    const size_t BIAS_B  = (size_t)WROWS*4;            //       4,608
    const size_t SC_B    = (size_t)N_*S_*VP_*VP_*4;    //      76,800
    u16*   fafbg = (u16*)(ws);
    u16*   xp    = (u16*)(ws + FAFBG_B);
    u16*   xpT   = (u16*)(ws + FAFBG_B + XP_B);
    u16*   Wb    = (u16*)(ws + FAFBG_B + 2*XP_B);
    float* biasv = (float*)(ws + FAFBG_B + 2*XP_B + WB_B);
    float* scores= (float*)(ws + FAFBG_B + 2*XP_B + WB_B + BIAS_B);
    float* att   = (float*)(ws + FAFBG_B + 2*XP_B + WB_B + BIAS_B + SC_B);
    float* scale = (float*)(ws + FAFBG_B + 2*XP_B + WB_B + BIAS_B + 2*SC_B);
    float* shift = scale + C_;

    k_conv_e<<<4096, 256, 0, stream>>>(x, w_e, b_e, xp);
    k_packW<<<WROWS, 256, 0, stream>>>(wa, wb, wd, ba, bb, Wb, biasv);
    k_tr<<<5120, 256, 0, stream>>>(xp, xpT);
    k_gemm<<<5760, 256, 0, stream>>>(Wb, xpT, biasv, fafbg);
    hipMemsetAsync(scores, 0, SC_B, stream);
    k_scores_mfma<<<N_*S_*32, 256, 0, stream>>>(fafbg, scores);
    k_att<<<N_*S_, 32, 0, stream>>>(scores, PA, A_fix, att);
    k_comb<<<N_*C_, 256, 0, stream>>>(fafbg, att, bd, out);
    k_bnstat<<<C_, 256, 0, stream>>>(out, gamma, beta, scale, shift);
    k_final<<<2048, 256, 0, stream>>>(out, xp, scale, shift);
}